// Round 1
// 907.646 us; speedup vs baseline: 1.0609x; 1.0609x over previous
//
#include <hip/hip_runtime.h>
#include <math.h>

#define B_ 8
#define T_ 1024
#define F_ 1024
#define H_ 16
#define D_ 64

typedef __bf16 bf16x8 __attribute__((ext_vector_type(8)));
typedef float f32x4 __attribute__((ext_vector_type(4)));
typedef unsigned short u16x8 __attribute__((ext_vector_type(8)));

__device__ __forceinline__ unsigned short f2bf(float f) {
    union { float f; unsigned u; } v; v.f = f;
    unsigned r = v.u + 0x7fffu + ((v.u >> 16) & 1u);
    return (unsigned short)(r >> 16);
}

__device__ __forceinline__ void gld16(const void* g, void* l) {
    __builtin_amdgcn_global_load_lds(
        (const __attribute__((address_space(1))) void*)g,
        (__attribute__((address_space(3))) void*)l, 16, 0, 0);
}

// f(row) for 4-chunk (64B) rows: involution on chunk index, uses row&15 only
__device__ __forceinline__ int swz4(int row15) {
    return (row15 ^ (row15 >> 2)) & 3;
}

// ---------------------------------------------------------------------------
// fp32 -> bf16 conversion, 8 elems/thread
// ---------------------------------------------------------------------------
__global__ __launch_bounds__(256) void cvt_f32_bf16(
    const float* __restrict__ in, unsigned short* __restrict__ out, int n8)
{
    int i = blockIdx.x * 256 + threadIdx.x;
    if (i >= n8) return;
    const float4* p = (const float4*)in + (size_t)i * 2;
    float4 x = p[0], y = p[1];
    u16x8 o;
    o[0] = f2bf(x.x); o[1] = f2bf(x.y); o[2] = f2bf(x.z); o[3] = f2bf(x.w);
    o[4] = f2bf(y.x); o[5] = f2bf(y.y); o[6] = f2bf(y.z); o[7] = f2bf(y.w);
    ((u16x8*)out)[i] = o;
}

// ---------------------------------------------------------------------------
// QKV projection: Xb[8192,1024]bf16 @ Wb^T (Wb[3072,1024]bf16) + bias(fp32)
// -> qb,kb bf16 [B,H,T,D]; vb bf16 [B,H,D,T] (transposed for PV GEMM)
// 128x128 tile, BK=32, 4 waves each 64x64, global_load_lds w=16, XOR swizzle.
// ---------------------------------------------------------------------------
__global__ __launch_bounds__(256) void qkv_gemm(
    const unsigned short* __restrict__ A,
    const unsigned short* __restrict__ Bw,
    const float* __restrict__ bias,
    unsigned short* __restrict__ qb,
    unsigned short* __restrict__ kb,
    unsigned short* __restrict__ vb)
{
    __shared__ __align__(16) unsigned short As[128 * 32];
    __shared__ __align__(16) unsigned short Bs[128 * 32];
    const int K = 1024;
    int tid = threadIdx.x;
    int lane = tid & 63, wave = tid >> 6;
    int wr = wave >> 1, wc = wave & 1;
    int m0 = blockIdx.y * 128, n0 = blockIdx.x * 128;
    int col = lane & 15, quad = lane >> 4;
    int sw = swz4(col);
    // staging lane decomposition: 16 rows x 4 chunks(16B) per wave-instr
    int rl = lane >> 2;
    int lc = (lane & 3) ^ swz4(rl);

    f32x4 acc[4][4] = {};
    for (int kc = 0; kc < K; kc += 32) {
        __syncthreads();
        #pragma unroll
        for (int l = 0; l < 2; l++) {
            int ia = wave * 2 + l;
            gld16(A  + (size_t)(m0 + ia * 16 + rl) * K + kc + lc * 8, &As[ia * 512]);
            gld16(Bw + (size_t)(n0 + ia * 16 + rl) * K + kc + lc * 8, &Bs[ia * 512]);
        }
        __syncthreads();
        bf16x8 af[4], bg[4];
        #pragma unroll
        for (int mt = 0; mt < 4; mt++)
            af[mt] = *(const bf16x8*)&As[(wr * 64 + mt * 16 + col) * 32 + ((quad ^ sw)) * 8];
        #pragma unroll
        for (int nt = 0; nt < 4; nt++)
            bg[nt] = *(const bf16x8*)&Bs[(wc * 64 + nt * 16 + col) * 32 + ((quad ^ sw)) * 8];
        #pragma unroll
        for (int mt = 0; mt < 4; mt++)
            #pragma unroll
            for (int nt = 0; nt < 4; nt++)
                acc[mt][nt] = __builtin_amdgcn_mfma_f32_16x16x32_bf16(
                    af[mt], bg[nt], acc[mt][nt], 0, 0, 0);
    }
    // epilogue: n-tile (128-wide) never crosses the q/k/v 1024-boundaries
    int which = n0 >> 10;
    #pragma unroll
    for (int nt = 0; nt < 4; nt++) {
        int n = n0 + wc * 64 + nt * 16 + col;
        int hn = (n & 1023) >> 6, d = n & 63;
        float bn = bias[n];
        #pragma unroll
        for (int mt = 0; mt < 4; mt++) {
            #pragma unroll
            for (int r = 0; r < 4; r++) {
                int m = m0 + wr * 64 + mt * 16 + quad * 4 + r;
                int bb = m >> 10, t = m & 1023;
                unsigned short bf = f2bf(acc[mt][nt][r] + bn);
                if (which == 0)
                    qb[(size_t)((bb * H_ + hn) * T_ + t) * D_ + d] = bf;
                else if (which == 1)
                    kb[(size_t)((bb * H_ + hn) * T_ + t) * D_ + d] = bf;
                else
                    vb[(size_t)((bb * H_ + hn) * D_ + d) * T_ + t] = bf;
            }
        }
    }
}

// ---------------------------------------------------------------------------
// FUSED: scores + mask + softmax + (alpha write) + alpha@V.
// Block = (b,h,16 q-rows), 4 waves each own 256 keys for QK^T.
// After softmax, alpha rows live in registers: write fp32 alpha to global AND
// bf16 P into LDS (aliased over the dead K buffer, pitch 1032 -> 2-way banks).
// PV: per wave one 16-wide d tile; V [D,T] staged per-wave (16x128 chunks,
// XOR-chunk pre-swizzle) -> barrier-free PV loop (only vmcnt/lgkm waits).
// ---------------------------------------------------------------------------
__global__ __launch_bounds__(256) void fused_attn(
    const unsigned short* __restrict__ qb,
    const unsigned short* __restrict__ kb,
    const unsigned short* __restrict__ vb,
    const int* __restrict__ mask,
    float* __restrict__ alpha,
    unsigned short* __restrict__ attb)
{
    // U: phase1 = Ks[4][64*64] (16384 shorts); phase2/3 = P[16][1032] (16512)
    __shared__ __align__(16) unsigned short U[16 * 1032];
    __shared__ __align__(16) unsigned short Vs[4][2048]; // per-wave 16 x 128
    __shared__ __align__(16) unsigned short Qs[16 * 72]; // padded rows (144B)
    __shared__ float redmax[4][16];
    __shared__ float redsum[4][16];
    int b = blockIdx.z, h = blockIdx.y, q0 = blockIdx.x * 16;
    int tid = threadIdx.x, lane = tid & 63, wave = tid >> 6;
    int col = lane & 15, quad = lane >> 4;
    const unsigned short* qbase = qb + ((size_t)(b * H_ + h) * T_ + q0) * D_;
    const unsigned short* kbase = kb + ((size_t)(b * H_ + h) * T_) * D_;
    unsigned short* Ksw = &U[wave * 4096];

    if (tid < 128) {  // stage Q: 16 rows x 64 bf16
        int r = tid >> 3, c = tid & 7;
        *(u16x8*)&Qs[r * 72 + c * 8] = *(const u16x8*)&qbase[r * 64 + c * 8];
    }
    int krl = lane >> 3;              // 8 rows per wave-instr
    int klc = (lane & 7) ^ krl;       // pre-swizzled chunk (8x16B per 128B row)
    int sw8 = col & 7;
    f32x4 acc[4][4] = {};
    bf16x8 aq0, aq1;
    for (int it = 0; it < 4; it++) {
        int kr0 = wave * 256 + it * 64;
        #pragma unroll
        for (int j = 0; j < 8; j++)
            gld16(kbase + (size_t)(kr0 + j * 8 + krl) * 64 + klc * 8, &Ksw[j * 512]);
        __syncthreads();
        if (it == 0) {
            aq0 = *(const bf16x8*)&Qs[col * 72 + quad * 8];
            aq1 = *(const bf16x8*)&Qs[col * 72 + 32 + quad * 8];
        }
        #pragma unroll
        for (int ct = 0; ct < 4; ct++) {
            int r = ct * 16 + col;
            const unsigned short* kp = &Ksw[r * 64];
            bf16x8 b0 = *(const bf16x8*)&kp[(quad ^ sw8) * 8];
            bf16x8 b1 = *(const bf16x8*)&kp[((4 + quad) ^ sw8) * 8];
            acc[it][ct] = __builtin_amdgcn_mfma_f32_16x16x32_bf16(aq0, b0, acc[it][ct], 0, 0, 0);
            acc[it][ct] = __builtin_amdgcn_mfma_f32_16x16x32_bf16(aq1, b1, acc[it][ct], 0, 0, 0);
        }
        __syncthreads();
    }
    // scale + mask + row max (rows = quad*4+r, this wave's 256-key strip)
    const int* mrow = mask + b * T_;
    float mx[4] = {-INFINITY, -INFINITY, -INFINITY, -INFINITY};
    #pragma unroll
    for (int it = 0; it < 4; it++)
        #pragma unroll
        for (int ct = 0; ct < 4; ct++) {
            int k = wave * 256 + it * 64 + ct * 16 + col;
            bool m = mrow[k] != 0;
            #pragma unroll
            for (int r = 0; r < 4; r++) {
                float v = m ? -INFINITY : acc[it][ct][r] * 0.125f;
                acc[it][ct][r] = v;
                mx[r] = fmaxf(mx[r], v);
            }
        }
    #pragma unroll
    for (int r = 0; r < 4; r++) {
        mx[r] = fmaxf(mx[r], __shfl_xor(mx[r], 1, 64));
        mx[r] = fmaxf(mx[r], __shfl_xor(mx[r], 2, 64));
        mx[r] = fmaxf(mx[r], __shfl_xor(mx[r], 4, 64));
        mx[r] = fmaxf(mx[r], __shfl_xor(mx[r], 8, 64));
    }
    if (col == 0)
        #pragma unroll
        for (int r = 0; r < 4; r++) redmax[wave][quad * 4 + r] = mx[r];
    __syncthreads();
    float gm[4];
    #pragma unroll
    for (int r = 0; r < 4; r++) {
        int row = quad * 4 + r;
        gm[r] = fmaxf(fmaxf(redmax[0][row], redmax[1][row]),
                      fmaxf(redmax[2][row], redmax[3][row]));
    }
    float sm[4] = {0.f, 0.f, 0.f, 0.f};
    #pragma unroll
    for (int it = 0; it < 4; it++)
        #pragma unroll
        for (int ct = 0; ct < 4; ct++)
            #pragma unroll
            for (int r = 0; r < 4; r++) {
                float e = __expf(acc[it][ct][r] - gm[r]);
                acc[it][ct][r] = e;
                sm[r] += e;
            }
    #pragma unroll
    for (int r = 0; r < 4; r++) {
        sm[r] += __shfl_xor(sm[r], 1, 64);
        sm[r] += __shfl_xor(sm[r], 2, 64);
        sm[r] += __shfl_xor(sm[r], 4, 64);
        sm[r] += __shfl_xor(sm[r], 8, 64);
    }
    if (col == 0)
        #pragma unroll
        for (int r = 0; r < 4; r++) redsum[wave][quad * 4 + r] = sm[r];
    __syncthreads();
    float inv[4];
    #pragma unroll
    for (int r = 0; r < 4; r++) {
        int row = quad * 4 + r;
        inv[r] = 1.0f / (redsum[0][row] + redsum[1][row] + redsum[2][row] + redsum[3][row]);
    }
    // phase 2: alpha fp32 -> global; bf16 P -> LDS (U alias; pitch 1032 shorts)
    float* abase = alpha + ((size_t)(b * H_ + h) * T_ + q0) * T_;
    #pragma unroll
    for (int it = 0; it < 4; it++)
        #pragma unroll
        for (int ct = 0; ct < 4; ct++) {
            int k = wave * 256 + it * 64 + ct * 16 + col;
            #pragma unroll
            for (int r = 0; r < 4; r++) {
                float v = acc[it][ct][r] * inv[r];
                abase[(size_t)(quad * 4 + r) * T_ + k] = v;
                U[(quad * 4 + r) * 1032 + k] = f2bf(v);
            }
        }
    __syncthreads();
    // phase 3: att(16q x 16d per wave) = P(16x1024) @ V^T, V chunks per-wave
    const unsigned short* vhead = vb + (size_t)(b * H_ + h) * D_ * T_;
    f32x4 oacc = {};
    for (int kc = 0; kc < T_; kc += 128) {
        // prior chunk's ds_reads must complete before overwriting Vs[wave]
        asm volatile("s_waitcnt lgkmcnt(0)" ::: "memory");
        __builtin_amdgcn_sched_barrier(0);
        #pragma unroll
        for (int i = 0; i < 4; i++) {
            int r = i * 4 + quad;  // row within this wave's 16-row V tile
            gld16(vhead + (size_t)(wave * 16 + r) * T_ + kc + (col ^ (r & 7)) * 8,
                  &Vs[wave][i * 512]);
        }
        asm volatile("s_waitcnt vmcnt(0)" ::: "memory");
        __builtin_amdgcn_sched_barrier(0);
        #pragma unroll
        for (int w = 0; w < 4; w++) {
            bf16x8 pa = *(const bf16x8*)&U[col * 1032 + kc + w * 32 + quad * 8];
            bf16x8 bv = *(const bf16x8*)&Vs[wave][col * 128 + (((w * 4 + quad) ^ (col & 7))) * 8];
            oacc = __builtin_amdgcn_mfma_f32_16x16x32_bf16(pa, bv, oacc, 0, 0, 0);
        }
    }
    #pragma unroll
    for (int r = 0; r < 4; r++) {
        int t = q0 + quad * 4 + r;
        attb[(size_t)(b * T_ + t) * F_ + h * D_ + wave * 16 + col] = f2bf(oacc[r]);
    }
}

// ---------------------------------------------------------------------------
// out = attb[8192,1024]bf16 @ Wob^T + bias -> fp32 d_out
// ---------------------------------------------------------------------------
__global__ __launch_bounds__(256) void out_gemm(
    const unsigned short* __restrict__ A,
    const unsigned short* __restrict__ Bw,
    const float* __restrict__ bias,
    float* __restrict__ out)
{
    __shared__ __align__(16) unsigned short As[128 * 32];
    __shared__ __align__(16) unsigned short Bs[128 * 32];
    const int K = 1024;
    int tid = threadIdx.x;
    int lane = tid & 63, wave = tid >> 6;
    int wr = wave >> 1, wc = wave & 1;
    int m0 = blockIdx.y * 128, n0 = blockIdx.x * 128;
    int col = lane & 15, quad = lane >> 4;
    int sw = swz4(col);
    int rl = lane >> 2;
    int lc = (lane & 3) ^ swz4(rl);
    f32x4 acc[4][4] = {};
    for (int kc = 0; kc < K; kc += 32) {
        __syncthreads();
        #pragma unroll
        for (int l = 0; l < 2; l++) {
            int ia = wave * 2 + l;
            gld16(A  + (size_t)(m0 + ia * 16 + rl) * K + kc + lc * 8, &As[ia * 512]);
            gld16(Bw + (size_t)(n0 + ia * 16 + rl) * K + kc + lc * 8, &Bs[ia * 512]);
        }
        __syncthreads();
        bf16x8 af[4], bg[4];
        #pragma unroll
        for (int mt = 0; mt < 4; mt++)
            af[mt] = *(const bf16x8*)&As[(wr * 64 + mt * 16 + col) * 32 + ((quad ^ sw)) * 8];
        #pragma unroll
        for (int nt = 0; nt < 4; nt++)
            bg[nt] = *(const bf16x8*)&Bs[(wc * 64 + nt * 16 + col) * 32 + ((quad ^ sw)) * 8];
        #pragma unroll
        for (int mt = 0; mt < 4; mt++)
            #pragma unroll
            for (int nt = 0; nt < 4; nt++)
                acc[mt][nt] = __builtin_amdgcn_mfma_f32_16x16x32_bf16(
                    af[mt], bg[nt], acc[mt][nt], 0, 0, 0);
    }
    #pragma unroll
    for (int nt = 0; nt < 4; nt++) {
        int n = n0 + wc * 64 + nt * 16 + col;
        float bn = bias[n];
        #pragma unroll
        for (int mt = 0; mt < 4; mt++) {
            #pragma unroll
            for (int r = 0; r < 4; r++) {
                int m = m0 + wr * 64 + mt * 16 + quad * 4 + r;
                out[(size_t)m * F_ + n] = acc[mt][nt][r] + bn;
            }
        }
    }
}

extern "C" void kernel_launch(void* const* d_in, const int* in_sizes, int n_in,
                              void* d_out, int out_size, void* d_ws, size_t ws_size,
                              hipStream_t stream)
{
    const float* qkv   = (const float*)d_in[0];
    const int*   mask  = (const int*)d_in[1];
    const float* in_w  = (const float*)d_in[2];
    const float* in_b  = (const float*)d_in[3];
    const float* out_w = (const float*)d_in[4];
    const float* out_b = (const float*)d_in[5];
    float* out = (float*)d_out;
    const size_t NE = (size_t)B_ * T_ * F_;       // 8388608
    float* alpha = out + NE;

    unsigned short* ws   = (unsigned short*)d_ws;
    unsigned short* Xb   = ws;                    // 8388608
    unsigned short* Wib  = Xb  + NE;              // 3145728
    unsigned short* Wob  = Wib + 3 * F_ * F_;     // 1048576
    unsigned short* qb2  = Wob + (size_t)F_ * F_; // 8388608
    unsigned short* kb2  = qb2 + NE;
    unsigned short* vb2  = kb2 + NE;
    unsigned short* attb = vb2 + NE;

    cvt_f32_bf16<<<dim3((int)(NE / 8 / 256)), 256, 0, stream>>>(qkv, Xb, (int)(NE / 8));
    cvt_f32_bf16<<<dim3(3 * F_ * F_ / 8 / 256), 256, 0, stream>>>(in_w, Wib, 3 * F_ * F_ / 8);
    cvt_f32_bf16<<<dim3(F_ * F_ / 8 / 256), 256, 0, stream>>>(out_w, Wob, F_ * F_ / 8);

    qkv_gemm<<<dim3(24, 64), 256, 0, stream>>>(Xb, Wib, in_b, qb2, kb2, vb2);
    fused_attn<<<dim3(64, H_, B_), 256, 0, stream>>>(qb2, kb2, vb2, mask, alpha, attb);
    out_gemm<<<dim3(8, 64), 256, 0, stream>>>(attb, Wob, out_b, out);
}

// Round 2
// 905.836 us; speedup vs baseline: 1.0631x; 1.0020x over previous
//
#include <hip/hip_runtime.h>
#include <math.h>

#define B_ 8
#define T_ 1024
#define F_ 1024
#define H_ 16
#define D_ 64

typedef __bf16 bf16x8 __attribute__((ext_vector_type(8)));
typedef float f32x4 __attribute__((ext_vector_type(4)));
typedef unsigned short u16x8 __attribute__((ext_vector_type(8)));

__device__ __forceinline__ unsigned short f2bf(float f) {
    union { float f; unsigned u; } v; v.f = f;
    unsigned r = v.u + 0x7fffu + ((v.u >> 16) & 1u);
    return (unsigned short)(r >> 16);
}

__device__ __forceinline__ void gld16(const void* g, void* l) {
    __builtin_amdgcn_global_load_lds(
        (const __attribute__((address_space(1))) void*)g,
        (__attribute__((address_space(3))) void*)l, 16, 0, 0);
}

// f(row) for 4-chunk (64B) rows: involution on chunk index, uses row&15 only
__device__ __forceinline__ int swz4(int row15) {
    return (row15 ^ (row15 >> 2)) & 3;
}

// ---------------------------------------------------------------------------
// fp32 -> bf16 conversion, 8 elems/thread
// ---------------------------------------------------------------------------
__global__ __launch_bounds__(256) void cvt_f32_bf16(
    const float* __restrict__ in, unsigned short* __restrict__ out, int n8)
{
    int i = blockIdx.x * 256 + threadIdx.x;
    if (i >= n8) return;
    const float4* p = (const float4*)in + (size_t)i * 2;
    float4 x = p[0], y = p[1];
    u16x8 o;
    o[0] = f2bf(x.x); o[1] = f2bf(x.y); o[2] = f2bf(x.z); o[3] = f2bf(x.w);
    o[4] = f2bf(y.x); o[5] = f2bf(y.y); o[6] = f2bf(y.z); o[7] = f2bf(y.w);
    ((u16x8*)out)[i] = o;
}

// ---------------------------------------------------------------------------
// QKV projection: Xb[8192,1024]bf16 @ Wb^T (Wb[3072,1024]bf16) + bias(fp32)
// -> qb,kb bf16 [B,H,T,D]; vb bf16 [B,H,D,T] (transposed for PV GEMM)
// 128x128 tile, BK=32, 4 waves each 64x64, global_load_lds w=16, XOR swizzle.
// ---------------------------------------------------------------------------
__global__ __launch_bounds__(256) void qkv_gemm(
    const unsigned short* __restrict__ A,
    const unsigned short* __restrict__ Bw,
    const float* __restrict__ bias,
    unsigned short* __restrict__ qb,
    unsigned short* __restrict__ kb,
    unsigned short* __restrict__ vb)
{
    __shared__ __align__(16) unsigned short As[128 * 32];
    __shared__ __align__(16) unsigned short Bs[128 * 32];
    const int K = 1024;
    int tid = threadIdx.x;
    int lane = tid & 63, wave = tid >> 6;
    int wr = wave >> 1, wc = wave & 1;
    int m0 = blockIdx.y * 128, n0 = blockIdx.x * 128;
    int col = lane & 15, quad = lane >> 4;
    int sw = swz4(col);
    // staging lane decomposition: 16 rows x 4 chunks(16B) per wave-instr
    int rl = lane >> 2;
    int lc = (lane & 3) ^ swz4(rl);

    f32x4 acc[4][4] = {};
    for (int kc = 0; kc < K; kc += 32) {
        __syncthreads();
        #pragma unroll
        for (int l = 0; l < 2; l++) {
            int ia = wave * 2 + l;
            gld16(A  + (size_t)(m0 + ia * 16 + rl) * K + kc + lc * 8, &As[ia * 512]);
            gld16(Bw + (size_t)(n0 + ia * 16 + rl) * K + kc + lc * 8, &Bs[ia * 512]);
        }
        __syncthreads();
        bf16x8 af[4], bg[4];
        #pragma unroll
        for (int mt = 0; mt < 4; mt++)
            af[mt] = *(const bf16x8*)&As[(wr * 64 + mt * 16 + col) * 32 + ((quad ^ sw)) * 8];
        #pragma unroll
        for (int nt = 0; nt < 4; nt++)
            bg[nt] = *(const bf16x8*)&Bs[(wc * 64 + nt * 16 + col) * 32 + ((quad ^ sw)) * 8];
        #pragma unroll
        for (int mt = 0; mt < 4; mt++)
            #pragma unroll
            for (int nt = 0; nt < 4; nt++)
                acc[mt][nt] = __builtin_amdgcn_mfma_f32_16x16x32_bf16(
                    af[mt], bg[nt], acc[mt][nt], 0, 0, 0);
    }
    // epilogue: n-tile (128-wide) never crosses the q/k/v 1024-boundaries
    int which = n0 >> 10;
    #pragma unroll
    for (int nt = 0; nt < 4; nt++) {
        int n = n0 + wc * 64 + nt * 16 + col;
        int hn = (n & 1023) >> 6, d = n & 63;
        float bn = bias[n];
        #pragma unroll
        for (int mt = 0; mt < 4; mt++) {
            #pragma unroll
            for (int r = 0; r < 4; r++) {
                int m = m0 + wr * 64 + mt * 16 + quad * 4 + r;
                int bb = m >> 10, t = m & 1023;
                unsigned short bf = f2bf(acc[mt][nt][r] + bn);
                if (which == 0)
                    qb[(size_t)((bb * H_ + hn) * T_ + t) * D_ + d] = bf;
                else if (which == 1)
                    kb[(size_t)((bb * H_ + hn) * T_ + t) * D_ + d] = bf;
                else
                    vb[(size_t)((bb * H_ + hn) * D_ + d) * T_ + t] = bf;
            }
        }
    }
}

// ---------------------------------------------------------------------------
// FUSED: scores + mask + softmax + (alpha write) + alpha@V.
// Block = (b,h,16 q-rows). Pipelined, barrier-free QK^T and PV:
//  - Q fragments loaded directly from global (no Qs LDS, no early barrier)
//  - K: per-wave PRIVATE 2-deep ring of 32-key tiles in U, counted vmcnt(4)
//  - V: per-wave double-buffered 64-key chunks, counted vmcnt(2); chunks 0/1
//    issued before softmax so L2 latency hides under exp/reductions
// Barriers remain only where cross-wave data flows: softmax reductions + P.
// ---------------------------------------------------------------------------
__global__ __launch_bounds__(256) void fused_attn(
    const unsigned short* __restrict__ qb,
    const unsigned short* __restrict__ kb,
    const unsigned short* __restrict__ vb,
    const int* __restrict__ mask,
    float* __restrict__ alpha,
    unsigned short* __restrict__ attb)
{
    // U: phase1 = per-wave K ring (4 waves x 2 bufs x 2048 shorts = 16384)
    //    phase2/3 = P bf16 [16][1032]  (16512 shorts)
    __shared__ __align__(16) unsigned short U[16 * 1032];
    __shared__ __align__(16) unsigned short Vs[4][2][1024]; // per-wave V dbuf
    __shared__ float redmax[4][16];
    __shared__ float redsum[4][16];
    int b = blockIdx.z, h = blockIdx.y, q0 = blockIdx.x * 16;
    int tid = threadIdx.x, lane = tid & 63, wave = tid >> 6;
    int col = lane & 15, quad = lane >> 4;
    const unsigned short* qbase = qb + ((size_t)(b * H_ + h) * T_ + q0) * D_;
    const unsigned short* kbase = kb + ((size_t)(b * H_ + h) * T_) * D_;

    // Q fragments straight from global (issued first so later counted waits
    // leave them covered by the compiler's own register-use waitcnt)
    bf16x8 aq0 = *(const bf16x8*)&qbase[col * 64 + quad * 8];
    bf16x8 aq1 = *(const bf16x8*)&qbase[col * 64 + 32 + quad * 8];

    int krl = lane >> 3;              // 8 rows per gld16
    int klc = (lane & 7) ^ krl;       // pre-swizzled 16B chunk within 128B row
    int sw8 = col & 7;
    unsigned short* Kb0 = &U[wave * 4096];
    unsigned short* Kb1 = Kb0 + 2048;

    // prologue: prefetch K tiles 0 and 1 (per-wave private, no barrier)
    #pragma unroll
    for (int j = 0; j < 4; j++)
        gld16(kbase + (size_t)(wave * 256 + j * 8 + krl) * 64 + klc * 8, Kb0 + j * 512);
    #pragma unroll
    for (int j = 0; j < 4; j++)
        gld16(kbase + (size_t)(wave * 256 + 32 + j * 8 + krl) * 64 + klc * 8, Kb1 + j * 512);

    f32x4 acc[8][2] = {};
    #pragma unroll
    for (int it = 0; it < 8; it++) {
        if (it < 7) { asm volatile("s_waitcnt vmcnt(4)" ::: "memory"); }
        else        { asm volatile("s_waitcnt vmcnt(0)" ::: "memory"); }
        __builtin_amdgcn_sched_barrier(0);
        const unsigned short* Kb = (it & 1) ? Kb1 : Kb0;
        #pragma unroll
        for (int ct = 0; ct < 2; ct++) {
            const unsigned short* kp = Kb + (ct * 16 + col) * 64;
            bf16x8 b0 = *(const bf16x8*)&kp[(quad ^ sw8) * 8];
            bf16x8 b1 = *(const bf16x8*)&kp[((4 + quad) ^ sw8) * 8];
            acc[it][ct] = __builtin_amdgcn_mfma_f32_16x16x32_bf16(aq0, b0, acc[it][ct], 0, 0, 0);
            acc[it][ct] = __builtin_amdgcn_mfma_f32_16x16x32_bf16(aq1, b1, acc[it][ct], 0, 0, 0);
        }
        __builtin_amdgcn_sched_barrier(0);
        if (it < 6) {  // refill the buffer just consumed with tile it+2
            unsigned short* Kn = (it & 1) ? Kb1 : Kb0;
            #pragma unroll
            for (int j = 0; j < 4; j++)
                gld16(kbase + (size_t)(wave * 256 + (it + 2) * 32 + j * 8 + krl) * 64 + klc * 8,
                      Kn + j * 512);
        }
    }

    // prefetch V chunks 0,1 now — latency hides under softmax
    const unsigned short* vhead = vb + (size_t)(b * H_ + h) * D_ * T_;
    int vrl = lane >> 3;
    int vswz = (lane & 7) ^ vrl;
    #pragma unroll
    for (int i = 0; i < 2; i++)
        gld16(vhead + (size_t)(wave * 16 + i * 8 + vrl) * T_ + vswz * 8, &Vs[wave][0][i * 512]);
    #pragma unroll
    for (int i = 0; i < 2; i++)
        gld16(vhead + (size_t)(wave * 16 + i * 8 + vrl) * T_ + 64 + vswz * 8, &Vs[wave][1][i * 512]);

    // scale + mask + row max (rows = quad*4+r, this wave's 256-key strip)
    const int* mrow = mask + b * T_;
    float mx[4] = {-INFINITY, -INFINITY, -INFINITY, -INFINITY};
    #pragma unroll
    for (int it = 0; it < 8; it++)
        #pragma unroll
        for (int ct = 0; ct < 2; ct++) {
            int k = wave * 256 + it * 32 + ct * 16 + col;
            bool m = mrow[k] != 0;
            #pragma unroll
            for (int r = 0; r < 4; r++) {
                float v = m ? -INFINITY : acc[it][ct][r] * 0.125f;
                acc[it][ct][r] = v;
                mx[r] = fmaxf(mx[r], v);
            }
        }
    #pragma unroll
    for (int r = 0; r < 4; r++) {
        mx[r] = fmaxf(mx[r], __shfl_xor(mx[r], 1, 64));
        mx[r] = fmaxf(mx[r], __shfl_xor(mx[r], 2, 64));
        mx[r] = fmaxf(mx[r], __shfl_xor(mx[r], 4, 64));
        mx[r] = fmaxf(mx[r], __shfl_xor(mx[r], 8, 64));
    }
    if (col == 0)
        #pragma unroll
        for (int r = 0; r < 4; r++) redmax[wave][quad * 4 + r] = mx[r];
    __syncthreads();
    float gm[4];
    #pragma unroll
    for (int r = 0; r < 4; r++) {
        int row = quad * 4 + r;
        gm[r] = fmaxf(fmaxf(redmax[0][row], redmax[1][row]),
                      fmaxf(redmax[2][row], redmax[3][row]));
    }
    float sm[4] = {0.f, 0.f, 0.f, 0.f};
    #pragma unroll
    for (int it = 0; it < 8; it++)
        #pragma unroll
        for (int ct = 0; ct < 2; ct++)
            #pragma unroll
            for (int r = 0; r < 4; r++) {
                float e = __expf(acc[it][ct][r] - gm[r]);
                acc[it][ct][r] = e;
                sm[r] += e;
            }
    #pragma unroll
    for (int r = 0; r < 4; r++) {
        sm[r] += __shfl_xor(sm[r], 1, 64);
        sm[r] += __shfl_xor(sm[r], 2, 64);
        sm[r] += __shfl_xor(sm[r], 4, 64);
        sm[r] += __shfl_xor(sm[r], 8, 64);
    }
    if (col == 0)
        #pragma unroll
        for (int r = 0; r < 4; r++) redsum[wave][quad * 4 + r] = sm[r];
    __syncthreads();
    float inv[4];
    #pragma unroll
    for (int r = 0; r < 4; r++) {
        int row = quad * 4 + r;
        inv[r] = 1.0f / (redsum[0][row] + redsum[1][row] + redsum[2][row] + redsum[3][row]);
    }
    // phase 2: alpha fp32 -> global; bf16 P -> LDS (U alias; pitch 1032 shorts)
    // (all waves passed both reduction barriers => all K-ring reads done)
    float* abase = alpha + ((size_t)(b * H_ + h) * T_ + q0) * T_;
    #pragma unroll
    for (int it = 0; it < 8; it++)
        #pragma unroll
        for (int ct = 0; ct < 2; ct++) {
            int k = wave * 256 + it * 32 + ct * 16 + col;
            #pragma unroll
            for (int r = 0; r < 4; r++) {
                float v = acc[it][ct][r] * inv[r];
                abase[(size_t)(quad * 4 + r) * T_ + k] = v;
                U[(quad * 4 + r) * 1032 + k] = f2bf(v);
            }
        }
    __syncthreads();   // P visible to all waves; drains V chunks 0,1 (landed)
    // phase 3: att(16q x 16d per wave) = P(16x1024) @ V^T
    // 64-key chunks, per-wave dbuf, counted vmcnt — no barriers
    f32x4 oacc = {};
    #pragma unroll
    for (int t = 0; t < 16; t++) {
        if (t < 15) { asm volatile("s_waitcnt vmcnt(2)" ::: "memory"); }
        else        { asm volatile("s_waitcnt vmcnt(0)" ::: "memory"); }
        __builtin_amdgcn_sched_barrier(0);
        const unsigned short* Vb = Vs[wave][t & 1];
        bf16x8 pa0 = *(const bf16x8*)&U[col * 1032 + t * 64 + quad * 8];
        bf16x8 pa1 = *(const bf16x8*)&U[col * 1032 + t * 64 + 32 + quad * 8];
        bf16x8 bv0 = *(const bf16x8*)&Vb[col * 64 + ((quad ^ sw8)) * 8];
        bf16x8 bv1 = *(const bf16x8*)&Vb[col * 64 + (((quad + 4) ^ sw8)) * 8];
        oacc = __builtin_amdgcn_mfma_f32_16x16x32_bf16(pa0, bv0, oacc, 0, 0, 0);
        oacc = __builtin_amdgcn_mfma_f32_16x16x32_bf16(pa1, bv1, oacc, 0, 0, 0);
        __builtin_amdgcn_sched_barrier(0);
        if (t < 14) {  // refill consumed buffer with chunk t+2
            #pragma unroll
            for (int i = 0; i < 2; i++)
                gld16(vhead + (size_t)(wave * 16 + i * 8 + vrl) * T_ + (t + 2) * 64 + vswz * 8,
                      &Vs[wave][t & 1][i * 512]);
        }
    }
    #pragma unroll
    for (int r = 0; r < 4; r++) {
        int t = q0 + quad * 4 + r;
        attb[(size_t)(b * T_ + t) * F_ + h * D_ + wave * 16 + col] = f2bf(oacc[r]);
    }
}

// ---------------------------------------------------------------------------
// out = attb[8192,1024]bf16 @ Wob^T + bias -> fp32 d_out
// ---------------------------------------------------------------------------
__global__ __launch_bounds__(256) void out_gemm(
    const unsigned short* __restrict__ A,
    const unsigned short* __restrict__ Bw,
    const float* __restrict__ bias,
    float* __restrict__ out)
{
    __shared__ __align__(16) unsigned short As[128 * 32];
    __shared__ __align__(16) unsigned short Bs[128 * 32];
    const int K = 1024;
    int tid = threadIdx.x;
    int lane = tid & 63, wave = tid >> 6;
    int wr = wave >> 1, wc = wave & 1;
    int m0 = blockIdx.y * 128, n0 = blockIdx.x * 128;
    int col = lane & 15, quad = lane >> 4;
    int sw = swz4(col);
    int rl = lane >> 2;
    int lc = (lane & 3) ^ swz4(rl);
    f32x4 acc[4][4] = {};
    for (int kc = 0; kc < K; kc += 32) {
        __syncthreads();
        #pragma unroll
        for (int l = 0; l < 2; l++) {
            int ia = wave * 2 + l;
            gld16(A  + (size_t)(m0 + ia * 16 + rl) * K + kc + lc * 8, &As[ia * 512]);
            gld16(Bw + (size_t)(n0 + ia * 16 + rl) * K + kc + lc * 8, &Bs[ia * 512]);
        }
        __syncthreads();
        bf16x8 af[4], bg[4];
        #pragma unroll
        for (int mt = 0; mt < 4; mt++)
            af[mt] = *(const bf16x8*)&As[(wr * 64 + mt * 16 + col) * 32 + ((quad ^ sw)) * 8];
        #pragma unroll
        for (int nt = 0; nt < 4; nt++)
            bg[nt] = *(const bf16x8*)&Bs[(wc * 64 + nt * 16 + col) * 32 + ((quad ^ sw)) * 8];
        #pragma unroll
        for (int mt = 0; mt < 4; mt++)
            #pragma unroll
            for (int nt = 0; nt < 4; nt++)
                acc[mt][nt] = __builtin_amdgcn_mfma_f32_16x16x32_bf16(
                    af[mt], bg[nt], acc[mt][nt], 0, 0, 0);
    }
    #pragma unroll
    for (int nt = 0; nt < 4; nt++) {
        int n = n0 + wc * 64 + nt * 16 + col;
        float bn = bias[n];
        #pragma unroll
        for (int mt = 0; mt < 4; mt++) {
            #pragma unroll
            for (int r = 0; r < 4; r++) {
                int m = m0 + wr * 64 + mt * 16 + quad * 4 + r;
                out[(size_t)m * F_ + n] = acc[mt][nt][r] + bn;
            }
        }
    }
}

extern "C" void kernel_launch(void* const* d_in, const int* in_sizes, int n_in,
                              void* d_out, int out_size, void* d_ws, size_t ws_size,
                              hipStream_t stream)
{
    const float* qkv   = (const float*)d_in[0];
    const int*   mask  = (const int*)d_in[1];
    const float* in_w  = (const float*)d_in[2];
    const float* in_b  = (const float*)d_in[3];
    const float* out_w = (const float*)d_in[4];
    const float* out_b = (const float*)d_in[5];
    float* out = (float*)d_out;
    const size_t NE = (size_t)B_ * T_ * F_;       // 8388608
    float* alpha = out + NE;

    unsigned short* ws   = (unsigned short*)d_ws;
    unsigned short* Xb   = ws;                    // 8388608
    unsigned short* Wib  = Xb  + NE;              // 3145728
    unsigned short* Wob  = Wib + 3 * F_ * F_;     // 1048576
    unsigned short* qb2  = Wob + (size_t)F_ * F_; // 8388608
    unsigned short* kb2  = qb2 + NE;
    unsigned short* vb2  = kb2 + NE;
    unsigned short* attb = vb2 + NE;

    cvt_f32_bf16<<<dim3((int)(NE / 8 / 256)), 256, 0, stream>>>(qkv, Xb, (int)(NE / 8));
    cvt_f32_bf16<<<dim3(3 * F_ * F_ / 8 / 256), 256, 0, stream>>>(in_w, Wib, 3 * F_ * F_ / 8);
    cvt_f32_bf16<<<dim3(F_ * F_ / 8 / 256), 256, 0, stream>>>(out_w, Wob, F_ * F_ / 8);

    qkv_gemm<<<dim3(24, 64), 256, 0, stream>>>(Xb, Wib, in_b, qb2, kb2, vb2);
    fused_attn<<<dim3(64, H_, B_), 256, 0, stream>>>(qb2, kb2, vb2, mask, alpha, attb);
    out_gemm<<<dim3(8, 64), 256, 0, stream>>>(attb, Wob, out_b, out);
}

// Round 3
// 902.716 us; speedup vs baseline: 1.0667x; 1.0035x over previous
//
#include <hip/hip_runtime.h>
#include <math.h>

#define B_ 8
#define T_ 1024
#define F_ 1024
#define H_ 16
#define D_ 64

typedef __bf16 bf16x8 __attribute__((ext_vector_type(8)));
typedef float f32x4 __attribute__((ext_vector_type(4)));
typedef unsigned short u16x8 __attribute__((ext_vector_type(8)));

__device__ __forceinline__ unsigned short f2bf(float f) {
    union { float f; unsigned u; } v; v.f = f;
    unsigned r = v.u + 0x7fffu + ((v.u >> 16) & 1u);
    return (unsigned short)(r >> 16);
}

__device__ __forceinline__ void gld16(const void* g, void* l) {
    __builtin_amdgcn_global_load_lds(
        (const __attribute__((address_space(1))) void*)g,
        (__attribute__((address_space(3))) void*)l, 16, 0, 0);
}

// f(row) for 4-chunk (64B) rows: involution on chunk index, uses row&15 only
__device__ __forceinline__ int swz4(int row15) {
    return (row15 ^ (row15 >> 2)) & 3;
}

// ---------------------------------------------------------------------------
// fp32 -> bf16 conversion for all three inputs in ONE launch.
// Ranges are block-aligned (na8, nb8, nc8 all multiples of 256).
// ---------------------------------------------------------------------------
__global__ __launch_bounds__(256) void cvt3(
    const float* __restrict__ a, unsigned short* __restrict__ oa, int na8,
    const float* __restrict__ b, unsigned short* __restrict__ ob, int nb8,
    const float* __restrict__ c, unsigned short* __restrict__ oc, int nc8)
{
    int i = blockIdx.x * 256 + threadIdx.x;
    const float* in; unsigned short* out;
    if (i < na8)            { in = a; out = oa; }
    else if (i < na8 + nb8) { in = b; out = ob; i -= na8; }
    else                    { in = c; out = oc; i -= na8 + nb8; if (i >= nc8) return; }
    const float4* p = (const float4*)in + (size_t)i * 2;
    float4 x = p[0], y = p[1];
    u16x8 o;
    o[0] = f2bf(x.x); o[1] = f2bf(x.y); o[2] = f2bf(x.z); o[3] = f2bf(x.w);
    o[4] = f2bf(y.x); o[5] = f2bf(y.y); o[6] = f2bf(y.z); o[7] = f2bf(y.w);
    ((u16x8*)out)[i] = o;
}

// ---------------------------------------------------------------------------
// QKV projection: Xb[8192,1024]bf16 @ Wb^T (Wb[3072,1024]bf16) + bias(fp32)
// -> qb,kb bf16 [B,H,T,D]; vb bf16 [B,H,D,T] (transposed for PV GEMM)
// 128x128 tile, BK=32, 4 waves each 64x64, global_load_lds w=16, XOR swizzle.
// 3-deep LDS ring: 2 tiles in flight, vmcnt(4) waits only the oldest, ONE raw
// s_barrier per K-step (T3+T4). XCD-chunked block swizzle (T1, 1536%8==0).
// ---------------------------------------------------------------------------
__global__ __launch_bounds__(256) void qkv_gemm(
    const unsigned short* __restrict__ A,
    const unsigned short* __restrict__ Bw,
    const float* __restrict__ bias,
    unsigned short* __restrict__ qb,
    unsigned short* __restrict__ kb,
    unsigned short* __restrict__ vb)
{
    __shared__ __align__(16) unsigned short As[3][128 * 32];
    __shared__ __align__(16) unsigned short Bs[3][128 * 32];
    const int K = 1024;
    int tid = threadIdx.x;
    int lane = tid & 63, wave = tid >> 6;
    int wr = wave >> 1, wc = wave & 1;
    int l = blockIdx.y * 24 + blockIdx.x;          // 1536 blocks
    int s = (l & 7) * 192 + (l >> 3);              // XCD chunk swizzle (bijective)
    int m0 = (s / 24) * 128, n0 = (s % 24) * 128;
    int col = lane & 15, quad = lane >> 4;
    int sw = swz4(col);
    int rl = lane >> 2;
    int lc = (lane & 3) ^ swz4(rl);

    #define QKV_STAGE(ri, kt) do {                                              \
        int kc_ = (kt) * 32;                                                    \
        _Pragma("unroll")                                                       \
        for (int ld = 0; ld < 2; ld++) {                                        \
            int ia = wave * 2 + ld;                                             \
            gld16(A  + (size_t)(m0 + ia * 16 + rl) * K + kc_ + lc * 8,          \
                  &As[ri][ia * 512]);                                           \
            gld16(Bw + (size_t)(n0 + ia * 16 + rl) * K + kc_ + lc * 8,          \
                  &Bs[ri][ia * 512]);                                           \
        }                                                                       \
    } while (0)

    QKV_STAGE(0, 0);
    QKV_STAGE(1, 1);

    f32x4 acc[4][4] = {};
    int ri = 0;
    for (int t = 0; t < 31; t++) {
        asm volatile("s_waitcnt vmcnt(4)" ::: "memory");   // tile t landed
        __builtin_amdgcn_sched_barrier(0);
        __builtin_amdgcn_s_barrier();                      // all waves' tile t landed
        bf16x8 af[4], bg[4];
        #pragma unroll
        for (int mt = 0; mt < 4; mt++)
            af[mt] = *(const bf16x8*)&As[ri][(wr * 64 + mt * 16 + col) * 32 + (quad ^ sw) * 8];
        #pragma unroll
        for (int nt = 0; nt < 4; nt++)
            bg[nt] = *(const bf16x8*)&Bs[ri][(wc * 64 + nt * 16 + col) * 32 + (quad ^ sw) * 8];
        int rn = ri + 2; if (rn >= 3) rn -= 3;
        if (t < 30) QKV_STAGE(rn, t + 2);                  // 2-ahead prefetch
        #pragma unroll
        for (int mt = 0; mt < 4; mt++)
            #pragma unroll
            for (int nt = 0; nt < 4; nt++)
                acc[mt][nt] = __builtin_amdgcn_mfma_f32_16x16x32_bf16(
                    af[mt], bg[nt], acc[mt][nt], 0, 0, 0);
        ri = ri + 1; if (ri >= 3) ri -= 3;
    }
    {   // peeled last K-step (tile 31 in buffer ri)
        asm volatile("s_waitcnt vmcnt(0)" ::: "memory");
        __builtin_amdgcn_sched_barrier(0);
        __builtin_amdgcn_s_barrier();
        bf16x8 af[4], bg[4];
        #pragma unroll
        for (int mt = 0; mt < 4; mt++)
            af[mt] = *(const bf16x8*)&As[ri][(wr * 64 + mt * 16 + col) * 32 + (quad ^ sw) * 8];
        #pragma unroll
        for (int nt = 0; nt < 4; nt++)
            bg[nt] = *(const bf16x8*)&Bs[ri][(wc * 64 + nt * 16 + col) * 32 + (quad ^ sw) * 8];
        #pragma unroll
        for (int mt = 0; mt < 4; mt++)
            #pragma unroll
            for (int nt = 0; nt < 4; nt++)
                acc[mt][nt] = __builtin_amdgcn_mfma_f32_16x16x32_bf16(
                    af[mt], bg[nt], acc[mt][nt], 0, 0, 0);
    }
    #undef QKV_STAGE
    // epilogue: n-tile (128-wide) never crosses the q/k/v 1024-boundaries
    int which = n0 >> 10;
    #pragma unroll
    for (int nt = 0; nt < 4; nt++) {
        int n = n0 + wc * 64 + nt * 16 + col;
        int hn = (n & 1023) >> 6, d = n & 63;
        float bn = bias[n];
        #pragma unroll
        for (int mt = 0; mt < 4; mt++) {
            #pragma unroll
            for (int r = 0; r < 4; r++) {
                int m = m0 + wr * 64 + mt * 16 + quad * 4 + r;
                int bb = m >> 10, t = m & 1023;
                unsigned short bf = f2bf(acc[mt][nt][r] + bn);
                if (which == 0)
                    qb[(size_t)((bb * H_ + hn) * T_ + t) * D_ + d] = bf;
                else if (which == 1)
                    kb[(size_t)((bb * H_ + hn) * T_ + t) * D_ + d] = bf;
                else
                    vb[(size_t)((bb * H_ + hn) * D_ + d) * T_ + t] = bf;
            }
        }
    }
}

// ---------------------------------------------------------------------------
// FUSED: scores + mask + softmax + (alpha write) + alpha@V.  (unchanged R2)
// ---------------------------------------------------------------------------
__global__ __launch_bounds__(256) void fused_attn(
    const unsigned short* __restrict__ qb,
    const unsigned short* __restrict__ kb,
    const unsigned short* __restrict__ vb,
    const int* __restrict__ mask,
    float* __restrict__ alpha,
    unsigned short* __restrict__ attb)
{
    // U: phase1 = per-wave K ring (4 waves x 2 bufs x 2048 shorts = 16384)
    //    phase2/3 = P bf16 [16][1032]  (16512 shorts)
    __shared__ __align__(16) unsigned short U[16 * 1032];
    __shared__ __align__(16) unsigned short Vs[4][2][1024]; // per-wave V dbuf
    __shared__ float redmax[4][16];
    __shared__ float redsum[4][16];
    int b = blockIdx.z, h = blockIdx.y, q0 = blockIdx.x * 16;
    int tid = threadIdx.x, lane = tid & 63, wave = tid >> 6;
    int col = lane & 15, quad = lane >> 4;
    const unsigned short* qbase = qb + ((size_t)(b * H_ + h) * T_ + q0) * D_;
    const unsigned short* kbase = kb + ((size_t)(b * H_ + h) * T_) * D_;

    bf16x8 aq0 = *(const bf16x8*)&qbase[col * 64 + quad * 8];
    bf16x8 aq1 = *(const bf16x8*)&qbase[col * 64 + 32 + quad * 8];

    int krl = lane >> 3;              // 8 rows per gld16
    int klc = (lane & 7) ^ krl;       // pre-swizzled 16B chunk within 128B row
    int sw8 = col & 7;
    unsigned short* Kb0 = &U[wave * 4096];
    unsigned short* Kb1 = Kb0 + 2048;

    #pragma unroll
    for (int j = 0; j < 4; j++)
        gld16(kbase + (size_t)(wave * 256 + j * 8 + krl) * 64 + klc * 8, Kb0 + j * 512);
    #pragma unroll
    for (int j = 0; j < 4; j++)
        gld16(kbase + (size_t)(wave * 256 + 32 + j * 8 + krl) * 64 + klc * 8, Kb1 + j * 512);

    f32x4 acc[8][2] = {};
    #pragma unroll
    for (int it = 0; it < 8; it++) {
        if (it < 7) { asm volatile("s_waitcnt vmcnt(4)" ::: "memory"); }
        else        { asm volatile("s_waitcnt vmcnt(0)" ::: "memory"); }
        __builtin_amdgcn_sched_barrier(0);
        const unsigned short* Kb = (it & 1) ? Kb1 : Kb0;
        #pragma unroll
        for (int ct = 0; ct < 2; ct++) {
            const unsigned short* kp = Kb + (ct * 16 + col) * 64;
            bf16x8 b0 = *(const bf16x8*)&kp[(quad ^ sw8) * 8];
            bf16x8 b1 = *(const bf16x8*)&kp[((4 + quad) ^ sw8) * 8];
            acc[it][ct] = __builtin_amdgcn_mfma_f32_16x16x32_bf16(aq0, b0, acc[it][ct], 0, 0, 0);
            acc[it][ct] = __builtin_amdgcn_mfma_f32_16x16x32_bf16(aq1, b1, acc[it][ct], 0, 0, 0);
        }
        __builtin_amdgcn_sched_barrier(0);
        if (it < 6) {
            unsigned short* Kn = (it & 1) ? Kb1 : Kb0;
            #pragma unroll
            for (int j = 0; j < 4; j++)
                gld16(kbase + (size_t)(wave * 256 + (it + 2) * 32 + j * 8 + krl) * 64 + klc * 8,
                      Kn + j * 512);
        }
    }

    // prefetch V chunks 0,1 now — latency hides under softmax
    const unsigned short* vhead = vb + (size_t)(b * H_ + h) * D_ * T_;
    int vrl = lane >> 3;
    int vswz = (lane & 7) ^ vrl;
    #pragma unroll
    for (int i = 0; i < 2; i++)
        gld16(vhead + (size_t)(wave * 16 + i * 8 + vrl) * T_ + vswz * 8, &Vs[wave][0][i * 512]);
    #pragma unroll
    for (int i = 0; i < 2; i++)
        gld16(vhead + (size_t)(wave * 16 + i * 8 + vrl) * T_ + 64 + vswz * 8, &Vs[wave][1][i * 512]);

    const int* mrow = mask + b * T_;
    float mx[4] = {-INFINITY, -INFINITY, -INFINITY, -INFINITY};
    #pragma unroll
    for (int it = 0; it < 8; it++)
        #pragma unroll
        for (int ct = 0; ct < 2; ct++) {
            int k = wave * 256 + it * 32 + ct * 16 + col;
            bool m = mrow[k] != 0;
            #pragma unroll
            for (int r = 0; r < 4; r++) {
                float v = m ? -INFINITY : acc[it][ct][r] * 0.125f;
                acc[it][ct][r] = v;
                mx[r] = fmaxf(mx[r], v);
            }
        }
    #pragma unroll
    for (int r = 0; r < 4; r++) {
        mx[r] = fmaxf(mx[r], __shfl_xor(mx[r], 1, 64));
        mx[r] = fmaxf(mx[r], __shfl_xor(mx[r], 2, 64));
        mx[r] = fmaxf(mx[r], __shfl_xor(mx[r], 4, 64));
        mx[r] = fmaxf(mx[r], __shfl_xor(mx[r], 8, 64));
    }
    if (col == 0)
        #pragma unroll
        for (int r = 0; r < 4; r++) redmax[wave][quad * 4 + r] = mx[r];
    __syncthreads();
    float gm[4];
    #pragma unroll
    for (int r = 0; r < 4; r++) {
        int row = quad * 4 + r;
        gm[r] = fmaxf(fmaxf(redmax[0][row], redmax[1][row]),
                      fmaxf(redmax[2][row], redmax[3][row]));
    }
    float sm[4] = {0.f, 0.f, 0.f, 0.f};
    #pragma unroll
    for (int it = 0; it < 8; it++)
        #pragma unroll
        for (int ct = 0; ct < 2; ct++)
            #pragma unroll
            for (int r = 0; r < 4; r++) {
                float e = __expf(acc[it][ct][r] - gm[r]);
                acc[it][ct][r] = e;
                sm[r] += e;
            }
    #pragma unroll
    for (int r = 0; r < 4; r++) {
        sm[r] += __shfl_xor(sm[r], 1, 64);
        sm[r] += __shfl_xor(sm[r], 2, 64);
        sm[r] += __shfl_xor(sm[r], 4, 64);
        sm[r] += __shfl_xor(sm[r], 8, 64);
    }
    if (col == 0)
        #pragma unroll
        for (int r = 0; r < 4; r++) redsum[wave][quad * 4 + r] = sm[r];
    __syncthreads();
    float inv[4];
    #pragma unroll
    for (int r = 0; r < 4; r++) {
        int row = quad * 4 + r;
        inv[r] = 1.0f / (redsum[0][row] + redsum[1][row] + redsum[2][row] + redsum[3][row]);
    }
    float* abase = alpha + ((size_t)(b * H_ + h) * T_ + q0) * T_;
    #pragma unroll
    for (int it = 0; it < 8; it++)
        #pragma unroll
        for (int ct = 0; ct < 2; ct++) {
            int k = wave * 256 + it * 32 + ct * 16 + col;
            #pragma unroll
            for (int r = 0; r < 4; r++) {
                float v = acc[it][ct][r] * inv[r];
                abase[(size_t)(quad * 4 + r) * T_ + k] = v;
                U[(quad * 4 + r) * 1032 + k] = f2bf(v);
            }
        }
    __syncthreads();   // P visible to all waves; drains V chunks 0,1 (landed)
    f32x4 oacc = {};
    #pragma unroll
    for (int t = 0; t < 16; t++) {
        if (t < 15) { asm volatile("s_waitcnt vmcnt(2)" ::: "memory"); }
        else        { asm volatile("s_waitcnt vmcnt(0)" ::: "memory"); }
        __builtin_amdgcn_sched_barrier(0);
        const unsigned short* Vb = Vs[wave][t & 1];
        bf16x8 pa0 = *(const bf16x8*)&U[col * 1032 + t * 64 + quad * 8];
        bf16x8 pa1 = *(const bf16x8*)&U[col * 1032 + t * 64 + 32 + quad * 8];
        bf16x8 bv0 = *(const bf16x8*)&Vb[col * 64 + ((quad ^ sw8)) * 8];
        bf16x8 bv1 = *(const bf16x8*)&Vb[col * 64 + (((quad + 4) ^ sw8)) * 8];
        oacc = __builtin_amdgcn_mfma_f32_16x16x32_bf16(pa0, bv0, oacc, 0, 0, 0);
        oacc = __builtin_amdgcn_mfma_f32_16x16x32_bf16(pa1, bv1, oacc, 0, 0, 0);
        __builtin_amdgcn_sched_barrier(0);
        if (t < 14) {
            #pragma unroll
            for (int i = 0; i < 2; i++)
                gld16(vhead + (size_t)(wave * 16 + i * 8 + vrl) * T_ + (t + 2) * 64 + vswz * 8,
                      &Vs[wave][t & 1][i * 512]);
        }
    }
    #pragma unroll
    for (int r = 0; r < 4; r++) {
        int t = q0 + quad * 4 + r;
        attb[(size_t)(b * T_ + t) * F_ + h * D_ + wave * 16 + col] = f2bf(oacc[r]);
    }
}

// ---------------------------------------------------------------------------
// out = attb[8192,1024]bf16 @ Wob^T + bias -> fp32 d_out
// Same 3-deep ring + counted vmcnt + XCD swizzle (512 blocks, %8==0).
// ---------------------------------------------------------------------------
__global__ __launch_bounds__(256) void out_gemm(
    const unsigned short* __restrict__ A,
    const unsigned short* __restrict__ Bw,
    const float* __restrict__ bias,
    float* __restrict__ out)
{
    __shared__ __align__(16) unsigned short As[3][128 * 32];
    __shared__ __align__(16) unsigned short Bs[3][128 * 32];
    const int K = 1024;
    int tid = threadIdx.x;
    int lane = tid & 63, wave = tid >> 6;
    int wr = wave >> 1, wc = wave & 1;
    int l = blockIdx.y * 8 + blockIdx.x;           // 512 blocks
    int s = (l & 7) * 64 + (l >> 3);               // XCD chunk swizzle (bijective)
    int m0 = (s / 8) * 128, n0 = (s % 8) * 128;
    int col = lane & 15, quad = lane >> 4;
    int sw = swz4(col);
    int rl = lane >> 2;
    int lc = (lane & 3) ^ swz4(rl);

    #define OUT_STAGE(ri, kt) do {                                              \
        int kc_ = (kt) * 32;                                                    \
        _Pragma("unroll")                                                       \
        for (int ld = 0; ld < 2; ld++) {                                        \
            int ia = wave * 2 + ld;                                             \
            gld16(A  + (size_t)(m0 + ia * 16 + rl) * K + kc_ + lc * 8,          \
                  &As[ri][ia * 512]);                                           \
            gld16(Bw + (size_t)(n0 + ia * 16 + rl) * K + kc_ + lc * 8,          \
                  &Bs[ri][ia * 512]);                                           \
        }                                                                       \
    } while (0)

    OUT_STAGE(0, 0);
    OUT_STAGE(1, 1);

    f32x4 acc[4][4] = {};
    int ri = 0;
    for (int t = 0; t < 31; t++) {
        asm volatile("s_waitcnt vmcnt(4)" ::: "memory");
        __builtin_amdgcn_sched_barrier(0);
        __builtin_amdgcn_s_barrier();
        bf16x8 af[4], bg[4];
        #pragma unroll
        for (int mt = 0; mt < 4; mt++)
            af[mt] = *(const bf16x8*)&As[ri][(wr * 64 + mt * 16 + col) * 32 + (quad ^ sw) * 8];
        #pragma unroll
        for (int nt = 0; nt < 4; nt++)
            bg[nt] = *(const bf16x8*)&Bs[ri][(wc * 64 + nt * 16 + col) * 32 + (quad ^ sw) * 8];
        int rn = ri + 2; if (rn >= 3) rn -= 3;
        if (t < 30) OUT_STAGE(rn, t + 2);
        #pragma unroll
        for (int mt = 0; mt < 4; mt++)
            #pragma unroll
            for (int nt = 0; nt < 4; nt++)
                acc[mt][nt] = __builtin_amdgcn_mfma_f32_16x16x32_bf16(
                    af[mt], bg[nt], acc[mt][nt], 0, 0, 0);
        ri = ri + 1; if (ri >= 3) ri -= 3;
    }
    {
        asm volatile("s_waitcnt vmcnt(0)" ::: "memory");
        __builtin_amdgcn_sched_barrier(0);
        __builtin_amdgcn_s_barrier();
        bf16x8 af[4], bg[4];
        #pragma unroll
        for (int mt = 0; mt < 4; mt++)
            af[mt] = *(const bf16x8*)&As[ri][(wr * 64 + mt * 16 + col) * 32 + (quad ^ sw) * 8];
        #pragma unroll
        for (int nt = 0; nt < 4; nt++)
            bg[nt] = *(const bf16x8*)&Bs[ri][(wc * 64 + nt * 16 + col) * 32 + (quad ^ sw) * 8];
        #pragma unroll
        for (int mt = 0; mt < 4; mt++)
            #pragma unroll
            for (int nt = 0; nt < 4; nt++)
                acc[mt][nt] = __builtin_amdgcn_mfma_f32_16x16x32_bf16(
                    af[mt], bg[nt], acc[mt][nt], 0, 0, 0);
    }
    #undef OUT_STAGE
    #pragma unroll
    for (int nt = 0; nt < 4; nt++) {
        int n = n0 + wc * 64 + nt * 16 + col;
        float bn = bias[n];
        #pragma unroll
        for (int mt = 0; mt < 4; mt++) {
            #pragma unroll
            for (int r = 0; r < 4; r++) {
                int m = m0 + wr * 64 + mt * 16 + quad * 4 + r;
                out[(size_t)m * F_ + n] = acc[mt][nt][r] + bn;
            }
        }
    }
}

extern "C" void kernel_launch(void* const* d_in, const int* in_sizes, int n_in,
                              void* d_out, int out_size, void* d_ws, size_t ws_size,
                              hipStream_t stream)
{
    const float* qkv   = (const float*)d_in[0];
    const int*   mask  = (const int*)d_in[1];
    const float* in_w  = (const float*)d_in[2];
    const float* in_b  = (const float*)d_in[3];
    const float* out_w = (const float*)d_in[4];
    const float* out_b = (const float*)d_in[5];
    float* out = (float*)d_out;
    const size_t NE = (size_t)B_ * T_ * F_;       // 8388608
    float* alpha = out + NE;

    unsigned short* ws   = (unsigned short*)d_ws;
    unsigned short* Xb   = ws;                    // 8388608
    unsigned short* Wib  = Xb  + NE;              // 3145728
    unsigned short* Wob  = Wib + 3 * F_ * F_;     // 1048576
    unsigned short* qb2  = Wob + (size_t)F_ * F_; // 8388608
    unsigned short* kb2  = qb2 + NE;
    unsigned short* vb2  = kb2 + NE;
    unsigned short* attb = vb2 + NE;

    const int na8 = (int)(NE / 8);                // 1048576
    const int nb8 = 3 * F_ * F_ / 8;              // 393216
    const int nc8 = F_ * F_ / 8;                  // 131072
    cvt3<<<dim3((na8 + nb8 + nc8) / 256), 256, 0, stream>>>(
        qkv, Xb, na8, in_w, Wib, nb8, out_w, Wob, nc8);

    qkv_gemm<<<dim3(24, 64), 256, 0, stream>>>(Xb, Wib, in_b, qb2, kb2, vb2);
    fused_attn<<<dim3(64, H_, B_), 256, 0, stream>>>(qb2, kb2, vb2, mask, alpha, attb);
    out_gemm<<<dim3(8, 64), 256, 0, stream>>>(attb, Wob, out_b, out);
}

// Round 4
// 897.612 us; speedup vs baseline: 1.0728x; 1.0057x over previous
//
#include <hip/hip_runtime.h>
#include <math.h>

#define B_ 8
#define T_ 1024
#define F_ 1024
#define H_ 16
#define D_ 64

typedef __bf16 bf16x8 __attribute__((ext_vector_type(8)));
typedef float f32x4 __attribute__((ext_vector_type(4)));
typedef unsigned short u16x8 __attribute__((ext_vector_type(8)));

__device__ __forceinline__ unsigned short f2bf(float f) {
    union { float f; unsigned u; } v; v.f = f;
    unsigned r = v.u + 0x7fffu + ((v.u >> 16) & 1u);
    return (unsigned short)(r >> 16);
}

__device__ __forceinline__ void gld16(const void* g, void* l) {
    __builtin_amdgcn_global_load_lds(
        (const __attribute__((address_space(1))) void*)g,
        (__attribute__((address_space(3))) void*)l, 16, 0, 0);
}

// f(row) for 4-chunk (64B) rows: involution on chunk index, uses row&15 only
__device__ __forceinline__ int swz4(int row15) {
    return (row15 ^ (row15 >> 2)) & 3;
}

// ---------------------------------------------------------------------------
// fp32 -> bf16 conversion for all three inputs in ONE launch.
// ---------------------------------------------------------------------------
__global__ __launch_bounds__(256) void cvt3(
    const float* __restrict__ a, unsigned short* __restrict__ oa, int na8,
    const float* __restrict__ b, unsigned short* __restrict__ ob, int nb8,
    const float* __restrict__ c, unsigned short* __restrict__ oc, int nc8)
{
    int i = blockIdx.x * 256 + threadIdx.x;
    const float* in; unsigned short* out;
    if (i < na8)            { in = a; out = oa; }
    else if (i < na8 + nb8) { in = b; out = ob; i -= na8; }
    else                    { in = c; out = oc; i -= na8 + nb8; if (i >= nc8) return; }
    const float4* p = (const float4*)in + (size_t)i * 2;
    float4 x = p[0], y = p[1];
    u16x8 o;
    o[0] = f2bf(x.x); o[1] = f2bf(x.y); o[2] = f2bf(x.z); o[3] = f2bf(x.w);
    o[4] = f2bf(y.x); o[5] = f2bf(y.y); o[6] = f2bf(y.z); o[7] = f2bf(y.w);
    ((u16x8*)out)[i] = o;
}

// ---------------------------------------------------------------------------
// QKV projection (unchanged R3: 3-deep ring, counted vmcnt, XCD swizzle)
// ---------------------------------------------------------------------------
__global__ __launch_bounds__(256) void qkv_gemm(
    const unsigned short* __restrict__ A,
    const unsigned short* __restrict__ Bw,
    const float* __restrict__ bias,
    unsigned short* __restrict__ qb,
    unsigned short* __restrict__ kb,
    unsigned short* __restrict__ vb)
{
    __shared__ __align__(16) unsigned short As[3][128 * 32];
    __shared__ __align__(16) unsigned short Bs[3][128 * 32];
    const int K = 1024;
    int tid = threadIdx.x;
    int lane = tid & 63, wave = tid >> 6;
    int wr = wave >> 1, wc = wave & 1;
    int l = blockIdx.y * 24 + blockIdx.x;          // 1536 blocks
    int s = (l & 7) * 192 + (l >> 3);              // XCD chunk swizzle (bijective)
    int m0 = (s / 24) * 128, n0 = (s % 24) * 128;
    int col = lane & 15, quad = lane >> 4;
    int sw = swz4(col);
    int rl = lane >> 2;
    int lc = (lane & 3) ^ swz4(rl);

    #define QKV_STAGE(ri, kt) do {                                              \
        int kc_ = (kt) * 32;                                                    \
        _Pragma("unroll")                                                       \
        for (int ld = 0; ld < 2; ld++) {                                        \
            int ia = wave * 2 + ld;                                             \
            gld16(A  + (size_t)(m0 + ia * 16 + rl) * K + kc_ + lc * 8,          \
                  &As[ri][ia * 512]);                                           \
            gld16(Bw + (size_t)(n0 + ia * 16 + rl) * K + kc_ + lc * 8,          \
                  &Bs[ri][ia * 512]);                                           \
        }                                                                       \
    } while (0)

    QKV_STAGE(0, 0);
    QKV_STAGE(1, 1);

    f32x4 acc[4][4] = {};
    int ri = 0;
    for (int t = 0; t < 31; t++) {
        asm volatile("s_waitcnt vmcnt(4)" ::: "memory");
        __builtin_amdgcn_sched_barrier(0);
        __builtin_amdgcn_s_barrier();
        bf16x8 af[4], bg[4];
        #pragma unroll
        for (int mt = 0; mt < 4; mt++)
            af[mt] = *(const bf16x8*)&As[ri][(wr * 64 + mt * 16 + col) * 32 + (quad ^ sw) * 8];
        #pragma unroll
        for (int nt = 0; nt < 4; nt++)
            bg[nt] = *(const bf16x8*)&Bs[ri][(wc * 64 + nt * 16 + col) * 32 + (quad ^ sw) * 8];
        int rn = ri + 2; if (rn >= 3) rn -= 3;
        if (t < 30) QKV_STAGE(rn, t + 2);
        #pragma unroll
        for (int mt = 0; mt < 4; mt++)
            #pragma unroll
            for (int nt = 0; nt < 4; nt++)
                acc[mt][nt] = __builtin_amdgcn_mfma_f32_16x16x32_bf16(
                    af[mt], bg[nt], acc[mt][nt], 0, 0, 0);
        ri = ri + 1; if (ri >= 3) ri -= 3;
    }
    {
        asm volatile("s_waitcnt vmcnt(0)" ::: "memory");
        __builtin_amdgcn_sched_barrier(0);
        __builtin_amdgcn_s_barrier();
        bf16x8 af[4], bg[4];
        #pragma unroll
        for (int mt = 0; mt < 4; mt++)
            af[mt] = *(const bf16x8*)&As[ri][(wr * 64 + mt * 16 + col) * 32 + (quad ^ sw) * 8];
        #pragma unroll
        for (int nt = 0; nt < 4; nt++)
            bg[nt] = *(const bf16x8*)&Bs[ri][(wc * 64 + nt * 16 + col) * 32 + (quad ^ sw) * 8];
        #pragma unroll
        for (int mt = 0; mt < 4; mt++)
            #pragma unroll
            for (int nt = 0; nt < 4; nt++)
                acc[mt][nt] = __builtin_amdgcn_mfma_f32_16x16x32_bf16(
                    af[mt], bg[nt], acc[mt][nt], 0, 0, 0);
    }
    #undef QKV_STAGE
    int which = n0 >> 10;
    #pragma unroll
    for (int nt = 0; nt < 4; nt++) {
        int n = n0 + wc * 64 + nt * 16 + col;
        int hn = (n & 1023) >> 6, d = n & 63;
        float bn = bias[n];
        #pragma unroll
        for (int mt = 0; mt < 4; mt++) {
            #pragma unroll
            for (int r = 0; r < 4; r++) {
                int m = m0 + wr * 64 + mt * 16 + quad * 4 + r;
                int bb = m >> 10, t = m & 1023;
                unsigned short bf = f2bf(acc[mt][nt][r] + bn);
                if (which == 0)
                    qb[(size_t)((bb * H_ + hn) * T_ + t) * D_ + d] = bf;
                else if (which == 1)
                    kb[(size_t)((bb * H_ + hn) * T_ + t) * D_ + d] = bf;
                else
                    vb[(size_t)((bb * H_ + hn) * D_ + d) * T_ + t] = bf;
            }
        }
    }
}

// ---------------------------------------------------------------------------
// FUSED attention, QBLK=32: block = (b,h,32 q-rows), 4 waves each own a
// 256-key strip. QK^T: per-wave private K ring (counted vmcnt). Softmax:
// cross-wave reduce via LDS. PV: per-wave PARTIAL over own strip — per 32-key
// chunk, transpose P regs through a tiny per-wave LDS buf ([32][40] shorts),
// A-frag read back [q][t-chunk]; V B-frags loaded straight from global
// (vb is [D,T] row-contiguous), pipelined 1 iter ahead. Cross-wave O reduce
// through LDS at the end. LDS 34KB -> 4 blocks/CU; V read once per block.
// ---------------------------------------------------------------------------
__global__ __launch_bounds__(256) void fused_attn(
    const unsigned short* __restrict__ qb,
    const unsigned short* __restrict__ kb,
    const unsigned short* __restrict__ vb,
    const int* __restrict__ mask,
    float* __restrict__ alpha,
    unsigned short* __restrict__ attb)
{
    // U (16512 shorts = 33KB), per-wave region = 4096 shorts (8KB):
    //   phase1: K ring (2 x 2048 shorts)
    //   phase3: transpose buf (32 x 40 shorts = 1280)
    //   reduce: O partial, 2048 floats (full region)
    __shared__ __align__(16) unsigned short U[16 * 1032];
    __shared__ float redmax[4][32];
    __shared__ float redsum[4][32];
    int b = blockIdx.z, h = blockIdx.y, q0 = blockIdx.x * 32;
    int tid = threadIdx.x, lane = tid & 63, wave = tid >> 6;
    int col = lane & 15, quad = lane >> 4;
    const unsigned short* qbase = qb + ((size_t)(b * H_ + h) * T_ + q0) * D_;
    const unsigned short* kbase = kb + ((size_t)(b * H_ + h) * T_) * D_;

    // Q fragments for both 16-row groups, straight from global
    bf16x8 aq[2][2];
    #pragma unroll
    for (int qg = 0; qg < 2; qg++) {
        aq[qg][0] = *(const bf16x8*)&qbase[(qg * 16 + col) * 64 + quad * 8];
        aq[qg][1] = *(const bf16x8*)&qbase[(qg * 16 + col) * 64 + 32 + quad * 8];
    }

    int krl = lane >> 3;              // 8 rows per gld16
    int klc = (lane & 7) ^ krl;       // pre-swizzled 16B chunk within 128B row
    int sw8 = col & 7;
    unsigned short* Kb0 = &U[wave * 4096];
    unsigned short* Kb1 = Kb0 + 2048;

    // prefetch K tiles 0,1 (group-order fenced so vmcnt counting is exact)
    #pragma unroll
    for (int j = 0; j < 4; j++)
        gld16(kbase + (size_t)(wave * 256 + j * 8 + krl) * 64 + klc * 8, Kb0 + j * 512);
    __builtin_amdgcn_sched_barrier(0);
    #pragma unroll
    for (int j = 0; j < 4; j++)
        gld16(kbase + (size_t)(wave * 256 + 32 + j * 8 + krl) * 64 + klc * 8, Kb1 + j * 512);
    __builtin_amdgcn_sched_barrier(0);

    f32x4 acc[2][8][2] = {};
    #pragma unroll
    for (int it = 0; it < 8; it++) {
        if (it < 7) { asm volatile("s_waitcnt vmcnt(4)" ::: "memory"); }
        else        { asm volatile("s_waitcnt vmcnt(0)" ::: "memory"); }
        __builtin_amdgcn_sched_barrier(0);
        const unsigned short* Kb = (it & 1) ? Kb1 : Kb0;
        #pragma unroll
        for (int ct = 0; ct < 2; ct++) {
            const unsigned short* kp = Kb + (ct * 16 + col) * 64;
            bf16x8 b0 = *(const bf16x8*)&kp[(quad ^ sw8) * 8];
            bf16x8 b1 = *(const bf16x8*)&kp[((4 + quad) ^ sw8) * 8];
            #pragma unroll
            for (int qg = 0; qg < 2; qg++) {
                acc[qg][it][ct] = __builtin_amdgcn_mfma_f32_16x16x32_bf16(
                    aq[qg][0], b0, acc[qg][it][ct], 0, 0, 0);
                acc[qg][it][ct] = __builtin_amdgcn_mfma_f32_16x16x32_bf16(
                    aq[qg][1], b1, acc[qg][it][ct], 0, 0, 0);
            }
        }
        __builtin_amdgcn_sched_barrier(0);
        if (it < 6) {
            unsigned short* Kn = (it & 1) ? Kb1 : Kb0;
            #pragma unroll
            for (int j = 0; j < 4; j++)
                gld16(kbase + (size_t)(wave * 256 + (it + 2) * 32 + j * 8 + krl) * 64 + klc * 8,
                      Kn + j * 512);
            __builtin_amdgcn_sched_barrier(0);
        }
    }

    // scale + mask + row max
    const int* mrow = mask + b * T_;
    float mx[2][4] = {{-INFINITY, -INFINITY, -INFINITY, -INFINITY},
                      {-INFINITY, -INFINITY, -INFINITY, -INFINITY}};
    #pragma unroll
    for (int it = 0; it < 8; it++)
        #pragma unroll
        for (int ct = 0; ct < 2; ct++) {
            int k = wave * 256 + it * 32 + ct * 16 + col;
            bool m = mrow[k] != 0;
            #pragma unroll
            for (int qg = 0; qg < 2; qg++)
                #pragma unroll
                for (int r = 0; r < 4; r++) {
                    float v = m ? -INFINITY : acc[qg][it][ct][r] * 0.125f;
                    acc[qg][it][ct][r] = v;
                    mx[qg][r] = fmaxf(mx[qg][r], v);
                }
        }
    #pragma unroll
    for (int qg = 0; qg < 2; qg++)
        #pragma unroll
        for (int r = 0; r < 4; r++) {
            mx[qg][r] = fmaxf(mx[qg][r], __shfl_xor(mx[qg][r], 1, 64));
            mx[qg][r] = fmaxf(mx[qg][r], __shfl_xor(mx[qg][r], 2, 64));
            mx[qg][r] = fmaxf(mx[qg][r], __shfl_xor(mx[qg][r], 4, 64));
            mx[qg][r] = fmaxf(mx[qg][r], __shfl_xor(mx[qg][r], 8, 64));
        }
    if (col == 0)
        #pragma unroll
        for (int qg = 0; qg < 2; qg++)
            #pragma unroll
            for (int r = 0; r < 4; r++)
                redmax[wave][qg * 16 + quad * 4 + r] = mx[qg][r];
    __syncthreads();
    float gm[2][4];
    #pragma unroll
    for (int qg = 0; qg < 2; qg++)
        #pragma unroll
        for (int r = 0; r < 4; r++) {
            int row = qg * 16 + quad * 4 + r;
            gm[qg][r] = fmaxf(fmaxf(redmax[0][row], redmax[1][row]),
                              fmaxf(redmax[2][row], redmax[3][row]));
        }
    float sm[2][4] = {};
    #pragma unroll
    for (int it = 0; it < 8; it++)
        #pragma unroll
        for (int ct = 0; ct < 2; ct++)
            #pragma unroll
            for (int qg = 0; qg < 2; qg++)
                #pragma unroll
                for (int r = 0; r < 4; r++) {
                    float e = __expf(acc[qg][it][ct][r] - gm[qg][r]);
                    acc[qg][it][ct][r] = e;
                    sm[qg][r] += e;
                }
    #pragma unroll
    for (int qg = 0; qg < 2; qg++)
        #pragma unroll
        for (int r = 0; r < 4; r++) {
            sm[qg][r] += __shfl_xor(sm[qg][r], 1, 64);
            sm[qg][r] += __shfl_xor(sm[qg][r], 2, 64);
            sm[qg][r] += __shfl_xor(sm[qg][r], 4, 64);
            sm[qg][r] += __shfl_xor(sm[qg][r], 8, 64);
        }
    if (col == 0)
        #pragma unroll
        for (int qg = 0; qg < 2; qg++)
            #pragma unroll
            for (int r = 0; r < 4; r++)
                redsum[wave][qg * 16 + quad * 4 + r] = sm[qg][r];
    __syncthreads();
    float inv[2][4];
    #pragma unroll
    for (int qg = 0; qg < 2; qg++)
        #pragma unroll
        for (int r = 0; r < 4; r++) {
            int row = qg * 16 + quad * 4 + r;
            inv[qg][r] = 1.0f / (redsum[0][row] + redsum[1][row] +
                                 redsum[2][row] + redsum[3][row]);
        }

    // phase 3: alpha write + per-wave partial PV over own 256-key strip.
    // K ring is dead (own MFMAs consumed it) -> reuse region as transpose buf.
    float* abase = alpha + ((size_t)(b * H_ + h) * T_ + q0) * T_;
    const unsigned short* vhead = vb + (size_t)(b * H_ + h) * D_ * T_;
    unsigned short* tbuf = &U[wave * 4096];   // [32][40] shorts, 16B-aligned rows
    f32x4 oacc[2][4] = {};
    bf16x8 bfr[4];
    {   // prefetch V B-frags for chunk 0
        int t0 = wave * 256;
        #pragma unroll
        for (int dt = 0; dt < 4; dt++)
            bfr[dt] = *(const bf16x8*)&vhead[(size_t)(dt * 16 + col) * T_ + t0 + quad * 8];
    }
    #pragma unroll
    for (int it = 0; it < 8; it++) {
        int t0 = wave * 256 + it * 32;
        // alpha fp32 -> global (fire-and-forget) + bf16 P chunk -> tbuf
        #pragma unroll
        for (int ct = 0; ct < 2; ct++) {
            int k = t0 + ct * 16 + col;
            #pragma unroll
            for (int qg = 0; qg < 2; qg++)
                #pragma unroll
                for (int r = 0; r < 4; r++) {
                    float v = acc[qg][it][ct][r] * inv[qg][r];
                    int q = qg * 16 + quad * 4 + r;
                    abase[(size_t)q * T_ + k] = v;
                    tbuf[q * 40 + ct * 16 + col] = f2bf(v);
                }
        }
        // prefetch next chunk's V B-frags (issued before the lgkm wait so the
        // in-order vmcnt has a full iteration to retire earlier alpha stores)
        bf16x8 bfn[4];
        if (it < 7) {
            int t1 = t0 + 32;
            #pragma unroll
            for (int dt = 0; dt < 4; dt++)
                bfn[dt] = *(const bf16x8*)&vhead[(size_t)(dt * 16 + col) * T_ + t1 + quad * 8];
        }
        asm volatile("s_waitcnt lgkmcnt(0)" ::: "memory");
        __builtin_amdgcn_sched_barrier(0);
        bf16x8 afr[2];
        #pragma unroll
        for (int qg = 0; qg < 2; qg++)
            afr[qg] = *(const bf16x8*)&tbuf[(qg * 16 + col) * 40 + quad * 8];
        #pragma unroll
        for (int qg = 0; qg < 2; qg++)
            #pragma unroll
            for (int dt = 0; dt < 4; dt++)
                oacc[qg][dt] = __builtin_amdgcn_mfma_f32_16x16x32_bf16(
                    afr[qg], bfr[dt], oacc[qg][dt], 0, 0, 0);
        __builtin_amdgcn_sched_barrier(0);
        if (it < 7) {
            #pragma unroll
            for (int dt = 0; dt < 4; dt++) bfr[dt] = bfn[dt];
        }
    }
    // stash per-wave O partial ([32][64] f32 = full own region; tbuf dead)
    float* Ow = (float*)U + wave * 2048;
    #pragma unroll
    for (int qg = 0; qg < 2; qg++)
        #pragma unroll
        for (int dt = 0; dt < 4; dt++)
            #pragma unroll
            for (int r = 0; r < 4; r++)
                Ow[(qg * 16 + quad * 4 + r) * 64 + dt * 16 + col] = oacc[qg][dt][r];
    __syncthreads();
    // cross-wave reduce + attb write: 256 threads x 8 d-elems
    {
        int q = tid >> 3, dg = tid & 7;
        const float* O0 = (const float*)U;
        u16x8 o;
        #pragma unroll
        for (int j = 0; j < 8; j++) {
            int idx = q * 64 + dg * 8 + j;
            o[j] = f2bf(O0[idx] + O0[2048 + idx] + O0[4096 + idx] + O0[6144 + idx]);
        }
        *(u16x8*)&attb[(size_t)(b * T_ + q0 + q) * F_ + h * D_ + dg * 8] = o;
    }
}

// ---------------------------------------------------------------------------
// out = attb[8192,1024]bf16 @ Wob^T + bias -> fp32 d_out  (unchanged R3)
// ---------------------------------------------------------------------------
__global__ __launch_bounds__(256) void out_gemm(
    const unsigned short* __restrict__ A,
    const unsigned short* __restrict__ Bw,
    const float* __restrict__ bias,
    float* __restrict__ out)
{
    __shared__ __align__(16) unsigned short As[3][128 * 32];
    __shared__ __align__(16) unsigned short Bs[3][128 * 32];
    const int K = 1024;
    int tid = threadIdx.x;
    int lane = tid & 63, wave = tid >> 6;
    int wr = wave >> 1, wc = wave & 1;
    int l = blockIdx.y * 8 + blockIdx.x;           // 512 blocks
    int s = (l & 7) * 64 + (l >> 3);               // XCD chunk swizzle (bijective)
    int m0 = (s / 8) * 128, n0 = (s % 8) * 128;
    int col = lane & 15, quad = lane >> 4;
    int sw = swz4(col);
    int rl = lane >> 2;
    int lc = (lane & 3) ^ swz4(rl);

    #define OUT_STAGE(ri, kt) do {                                              \
        int kc_ = (kt) * 32;                                                    \
        _Pragma("unroll")                                                       \
        for (int ld = 0; ld < 2; ld++) {                                        \
            int ia = wave * 2 + ld;                                             \
            gld16(A  + (size_t)(m0 + ia * 16 + rl) * K + kc_ + lc * 8,          \
                  &As[ri][ia * 512]);                                           \
            gld16(Bw + (size_t)(n0 + ia * 16 + rl) * K + kc_ + lc * 8,          \
                  &Bs[ri][ia * 512]);                                           \
        }                                                                       \
    } while (0)

    OUT_STAGE(0, 0);
    OUT_STAGE(1, 1);

    f32x4 acc[4][4] = {};
    int ri = 0;
    for (int t = 0; t < 31; t++) {
        asm volatile("s_waitcnt vmcnt(4)" ::: "memory");
        __builtin_amdgcn_sched_barrier(0);
        __builtin_amdgcn_s_barrier();
        bf16x8 af[4], bg[4];
        #pragma unroll
        for (int mt = 0; mt < 4; mt++)
            af[mt] = *(const bf16x8*)&As[ri][(wr * 64 + mt * 16 + col) * 32 + (quad ^ sw) * 8];
        #pragma unroll
        for (int nt = 0; nt < 4; nt++)
            bg[nt] = *(const bf16x8*)&Bs[ri][(wc * 64 + nt * 16 + col) * 32 + (quad ^ sw) * 8];
        int rn = ri + 2; if (rn >= 3) rn -= 3;
        if (t < 30) OUT_STAGE(rn, t + 2);
        #pragma unroll
        for (int mt = 0; mt < 4; mt++)
            #pragma unroll
            for (int nt = 0; nt < 4; nt++)
                acc[mt][nt] = __builtin_amdgcn_mfma_f32_16x16x32_bf16(
                    af[mt], bg[nt], acc[mt][nt], 0, 0, 0);
        ri = ri + 1; if (ri >= 3) ri -= 3;
    }
    {
        asm volatile("s_waitcnt vmcnt(0)" ::: "memory");
        __builtin_amdgcn_sched_barrier(0);
        __builtin_amdgcn_s_barrier();
        bf16x8 af[4], bg[4];
        #pragma unroll
        for (int mt = 0; mt < 4; mt++)
            af[mt] = *(const bf16x8*)&As[ri][(wr * 64 + mt * 16 + col) * 32 + (quad ^ sw) * 8];
        #pragma unroll
        for (int nt = 0; nt < 4; nt++)
            bg[nt] = *(const bf16x8*)&Bs[ri][(wc * 64 + nt * 16 + col) * 32 + (quad ^ sw) * 8];
        #pragma unroll
        for (int mt = 0; mt < 4; mt++)
            #pragma unroll
            for (int nt = 0; nt < 4; nt++)
                acc[mt][nt] = __builtin_amdgcn_mfma_f32_16x16x32_bf16(
                    af[mt], bg[nt], acc[mt][nt], 0, 0, 0);
    }
    #undef OUT_STAGE
    #pragma unroll
    for (int nt = 0; nt < 4; nt++) {
        int n = n0 + wc * 64 + nt * 16 + col;
        float bn = bias[n];
        #pragma unroll
        for (int mt = 0; mt < 4; mt++) {
            #pragma unroll
            for (int r = 0; r < 4; r++) {
                int m = m0 + wr * 64 + mt * 16 + quad * 4 + r;
                out[(size_t)m * F_ + n] = acc[mt][nt][r] + bn;
            }
        }
    }
}

extern "C" void kernel_launch(void* const* d_in, const int* in_sizes, int n_in,
                              void* d_out, int out_size, void* d_ws, size_t ws_size,
                              hipStream_t stream)
{
    const float* qkv   = (const float*)d_in[0];
    const int*   mask  = (const int*)d_in[1];
    const float* in_w  = (const float*)d_in[2];
    const float* in_b  = (const float*)d_in[3];
    const float* out_w = (const float*)d_in[4];
    const float* out_b = (const float*)d_in[5];
    float* out = (float*)d_out;
    const size_t NE = (size_t)B_ * T_ * F_;       // 8388608
    float* alpha = out + NE;

    unsigned short* ws   = (unsigned short*)d_ws;
    unsigned short* Xb   = ws;                    // 8388608
    unsigned short* Wib  = Xb  + NE;              // 3145728
    unsigned short* Wob  = Wib + 3 * F_ * F_;     // 1048576
    unsigned short* qb2  = Wob + (size_t)F_ * F_; // 8388608
    unsigned short* kb2  = qb2 + NE;
    unsigned short* vb2  = kb2 + NE;
    unsigned short* attb = vb2 + NE;

    const int na8 = (int)(NE / 8);                // 1048576
    const int nb8 = 3 * F_ * F_ / 8;              // 393216
    const int nc8 = F_ * F_ / 8;                  // 131072
    cvt3<<<dim3((na8 + nb8 + nc8) / 256), 256, 0, stream>>>(
        qkv, Xb, na8, in_w, Wib, nb8, out_w, Wob, nc8);

    qkv_gemm<<<dim3(24, 64), 256, 0, stream>>>(Xb, Wib, in_b, qb2, kb2, vb2);
    fused_attn<<<dim3(32, H_, B_), 256, 0, stream>>>(qb2, kb2, vb2, mask, alpha, attb);
    out_gemm<<<dim3(8, 64), 256, 0, stream>>>(attb, Wob, out_b, out);
}